// Round 18
// baseline (365.793 us; speedup 1.0000x reference)
//
#include <hip/hip_runtime.h>
#include <cmath>

typedef __bf16 bf16_t;
typedef __bf16 bf16x8 __attribute__((ext_vector_type(8)));
typedef __bf16 bf16x4 __attribute__((ext_vector_type(4)));
typedef float f32x4 __attribute__((ext_vector_type(4)));

#define T_SEQ 2048
#define C_DIM 2048
#define H_NUM 16
#define HD    128
#define KK    2048  // reduction dim for both GEMMs

// ---------------- RoPE cos/sin table: [T][64] ----------------
__global__ void rope_table_kernel(float* __restrict__ ct, float* __restrict__ st) {
  int idx = blockIdx.x * 256 + threadIdx.x;   // T*64 = 131072
  int t = idx >> 6, i = idx & 63;
  double invf = pow(10000.0, -(double)i / 64.0);  // base^(-2i/hd)
  float ang = (float)t * (float)invf;             // fp32 rounding like reference
  ct[idx] = cosf(ang);
  st[idx] = sinf(ang);
}

// ---------------- fp32 -> bf16 elementwise ----------------
__global__ void convert_bf16_kernel(const float* __restrict__ in, bf16_t* __restrict__ out, int n4) {
  int i = blockIdx.x * 256 + threadIdx.x;
  if (i >= n4) return;
  const float4 v = reinterpret_cast<const float4*>(in)[i];
  bf16x4 o;
  o[0] = (bf16_t)v.x; o[1] = (bf16_t)v.y; o[2] = (bf16_t)v.z; o[3] = (bf16_t)v.w;
  reinterpret_cast<bf16x4*>(out)[i] = o;
}

// ---------------- transpose+convert: in[R][Cc] f32 -> out[Cc][R] bf16 ----------------
__global__ void transpose_convert_kernel(const float* __restrict__ in, bf16_t* __restrict__ out,
                                         int R, int Cc) {
  __shared__ __align__(16) bf16_t tile[32][33];
  int c0 = blockIdx.x * 32, r0 = blockIdx.y * 32;
  int tx = threadIdx.x, ty = threadIdx.y;
#pragma unroll
  for (int i = 0; i < 4; ++i)
    tile[ty + 8 * i][tx] = (bf16_t)in[(size_t)(r0 + ty + 8 * i) * Cc + c0 + tx];
  __syncthreads();
#pragma unroll
  for (int i = 0; i < 4; ++i)
    out[(size_t)(c0 + ty + 8 * i) * R + r0 + tx] = tile[tx][ty + 8 * i];
}

// ---------------- GEMM: A[M][K] bf16 @ Bt[N][K] bf16 -> epilogue ----------------
// r13 structure (measured best) with ONE change: __launch_bounds__(256,4).
// VGPR_Count=76 (measured r17) << 128 cap at 4 waves/SIMD; LDS 32KB*4=128KB
// <= 160KB -> 4 blocks/CU resident (was 2). Mechanism: the ~55% non-MFMA,
// non-VALU cycles are per-block barrier-drain stalls; independent blocks
// overlap them (m114 wave-level overlap across blocks).
template <int MODE>
__global__ __launch_bounds__(256, 4)
void gemm_bf16_kernel(const bf16_t* __restrict__ A, const bf16_t* __restrict__ Bt,
                      float* __restrict__ outF,
                      bf16_t* __restrict__ qws, bf16_t* __restrict__ kws,
                      bf16_t* __restrict__ vtws,
                      const float* __restrict__ ctab, const float* __restrict__ stab) {
  const int tid = threadIdx.x;
  const int l = tid & 63, w = tid >> 6;
  const int wr = w >> 1, wc = w & 1;
  const int lg = l >> 4, lr = l & 15;

  // per-XCD band mapping
  const int g = blockIdx.x & 7;
  const int q = blockIdx.x >> 3;
  int m0, n0;
  if (MODE == 0) {            // n-band: 6 cols per XCD, n-fast
    m0 = (q / 6) * 128;
    n0 = (g * 6 + (q % 6)) * 128;
  } else {                    // m-band: 4 rows per XCD, m-fast
    m0 = (g * 4 + (q & 3)) * 128;
    n0 = (q >> 2) * 128;
  }

  __shared__ __align__(16) bf16_t la[128][64];
  __shared__ __align__(16) bf16_t lb[128][64];

  f32x4 acc[4][4] = {};
  bf16x8 ra[4], rb[4];

  const bf16_t* Ab = A + (size_t)m0 * KK;
  const bf16_t* Bb = Bt + (size_t)n0 * KK;

#pragma unroll
  for (int c = 0; c < 4; ++c) {
    int p = tid + c * 256, row = p >> 3, kc = p & 7;
    ra[c] = *reinterpret_cast<const bf16x8*>(Ab + (size_t)row * KK + kc * 8);
    rb[c] = *reinterpret_cast<const bf16x8*>(Bb + (size_t)row * KK + kc * 8);
  }

  for (int kt = 0; kt < KK / 64; ++kt) {
    __syncthreads();  // previous tile's reads done
#pragma unroll
    for (int c = 0; c < 4; ++c) {
      int p = tid + c * 256, row = p >> 3;
      int kcw = (p & 7) ^ (row & 7);   // XOR layout: phys chunk holds global^row
      *reinterpret_cast<bf16x8*>(&la[row][kcw * 8]) = ra[c];
      *reinterpret_cast<bf16x8*>(&lb[row][kcw * 8]) = rb[c];
    }
    __syncthreads();
    if (kt + 1 < KK / 64) {  // prefetch next tile; latency hides under MFMAs
#pragma unroll
      for (int c = 0; c < 4; ++c) {
        int p = tid + c * 256, row = p >> 3, kc = p & 7;
        ra[c] = *reinterpret_cast<const bf16x8*>(Ab + (size_t)row * KK + (kt + 1) * 64 + kc * 8);
        rb[c] = *reinterpret_cast<const bf16x8*>(Bb + (size_t)row * KK + (kt + 1) * 64 + kc * 8);
      }
    }
#pragma unroll
    for (int ks = 0; ks < 2; ++ks) {
      bf16x8 af[4], bfr[4];
      const int pc = ((ks * 4 + lg) ^ (lr & 7)) * 8;  // matching read XOR
#pragma unroll
      for (int i = 0; i < 4; ++i) {
        af[i]  = *reinterpret_cast<const bf16x8*>(&la[wr * 64 + i * 16 + lr][pc]);
        bfr[i] = *reinterpret_cast<const bf16x8*>(&lb[wc * 64 + i * 16 + lr][pc]);
      }
#pragma unroll
      for (int mi = 0; mi < 4; ++mi)
#pragma unroll
        for (int ni = 0; ni < 4; ++ni)
          acc[mi][ni] = __builtin_amdgcn_mfma_f32_16x16x32_bf16(af[mi], bfr[ni], acc[mi][ni], 0, 0, 0);
    }
  }

  if (MODE == 0) {
    const int sec = n0 >> 11;           // 0=q 1=k 2=v (block never crosses sections)
    const int h = (n0 & 2047) >> 7;     // one head per 128-col block
#pragma unroll
    for (int mi = 0; mi < 4; ++mi) {
#pragma unroll
      for (int ni = 0; ni < 4; ++ni) {
        const int d = wc * 64 + ni * 16 + lr;   // 0..127
#pragma unroll
        for (int r = 0; r < 4; ++r) {
          const int m = m0 + wr * 64 + mi * 16 + lg * 4 + r;
          const int b = m >> 11, t = m & 2047;
          float val = acc[mi][ni][r];
          if (sec < 2) {
            // RoPE pair (d, d^1) sits in lane l^1 (D-frag col = lane&15)
            float partner = __shfl_xor(val, 1);
            const int fi = d >> 1;
            float cth = ctab[t * 64 + fi], sth = stab[t * 64 + fi];
            float ov = (d & 1) ? (val * cth + partner * sth)
                               : (val * cth - partner * sth);
            // q scale = (1/sqrt(128)) * log2(e): softmax runs in exp2 domain
            if (sec == 0) ov *= 0.127517445f;
            bf16_t* dst = (sec == 0) ? qws : kws;
            dst[((size_t)(b * H_NUM + h) * T_SEQ + t) * HD + d] = (bf16_t)ov;
          } else {
            // v stored transposed [b][h][d][t] so PV B-operand is kv-contiguous
            vtws[((size_t)(b * H_NUM + h) * HD + d) * T_SEQ + t] = (bf16_t)val;
          }
        }
      }
    }
  } else {
#pragma unroll
    for (int mi = 0; mi < 4; ++mi)
#pragma unroll
      for (int ni = 0; ni < 4; ++ni) {
        const int n = n0 + wc * 64 + ni * 16 + lr;
#pragma unroll
        for (int r = 0; r < 4; ++r) {
          const int m = m0 + wr * 64 + mi * 16 + lg * 4 + r;
          outF[(size_t)m * C_DIM + n] = acc[mi][ni][r];
        }
      }
  }
}

// ---------------- causal flash attention (v7: swapped-QK^T softmax) ----------------
// r13-measured best (total 357.3us): 512 paired blocks {31-p, p}, XCD-pinned
// (4 bh x 1MB K/V per XCD ~= L2; FETCH ~25MB), K dbuf + XOR swizzle, V-in-regs
// issued early, swapped QK^T (lane owns q-row), exp2 domain, defer-max,
// launch_bounds(256,2), VGPR 120, no spills. FROZEN.
__global__ __launch_bounds__(256, 2)
void attention_kernel(const bf16_t* __restrict__ qg, const bf16_t* __restrict__ kg,
                      const bf16_t* __restrict__ vtg, bf16_t* __restrict__ yg) {
  const int tid = threadIdx.x;
  const int l = tid & 63, w = tid >> 6;
  const int lg = l >> 4, lr = l & 15;

  const int g = blockIdx.x & 7;
  const int j = blockIdx.x >> 3;
  const int bh = 4 * g + (j >> 4);
  const int pair = j & 15;
  const int b = bh >> 4, h = bh & 15;

  __shared__ __align__(16) bf16_t lk[2][64][128];
  __shared__ __align__(16) bf16_t lp[4][16][72];   // per-wave P [q][kv], +8 pad

  const bf16_t* qp = qg + (size_t)bh * T_SEQ * HD;
  const bf16_t* kp = kg + (size_t)bh * T_SEQ * HD;
  const bf16_t* vp = vtg + (size_t)bh * HD * T_SEQ;

#pragma unroll 1
  for (int half = 0; half < 2; ++half) {
    const int qt = (half == 0) ? (31 - pair) : pair;
    const int qbase = qt * 64 + w * 16;

    bf16x8 qf[4];
#pragma unroll
    for (int dk = 0; dk < 4; ++dk)
      qf[dk] = *reinterpret_cast<const bf16x8*>(qp + (size_t)(qbase + lr) * HD + dk * 32 + lg * 8);

    f32x4 o[8] = {};
    float mrun = -1e30f, lrun = 0.f;   // scalar: this lane's q-row = qbase+lr

    // prologue: stage K tile 0 into lk[0]
    bf16x8 kreg[4];
#pragma unroll
    for (int c = 0; c < 4; ++c) {
      int p = tid + c * 256, row = p >> 4, ch = p & 15;
      kreg[c] = *reinterpret_cast<const bf16x8*>(kp + (size_t)row * HD + ch * 8);
    }
    __syncthreads();  // prior half's lk reads complete before overwrite
#pragma unroll
    for (int c = 0; c < 4; ++c) {
      int p = tid + c * 256, row = p >> 4, ch = (p & 15) ^ (row & 7);
      *reinterpret_cast<bf16x8*>(&lk[0][row][ch * 8]) = kreg[c];
    }
    __syncthreads();

#pragma unroll 1
    for (int kt = 0; kt <= qt; ++kt) {
      const int cur = kt & 1;
      const int kv0 = kt * 64;

      // 1) V fragments for THIS tile: issue first (needed mid-iteration)
      bf16x8 vf[16];
#pragma unroll
      for (int cc = 0; cc < 8; ++cc)
#pragma unroll
        for (int ks = 0; ks < 2; ++ks)
          vf[cc * 2 + ks] = *reinterpret_cast<const bf16x8*>(
              vp + (size_t)(cc * 16 + lr) * T_SEQ + kv0 + ks * 32 + lg * 8);

      // 2) K prefetch for NEXT tile (stays in flight past the V wait)
      if (kt < qt) {
#pragma unroll
        for (int c = 0; c < 4; ++c) {
          int p = tid + c * 256, row = p >> 4, ch = p & 15;
          kreg[c] = *reinterpret_cast<const bf16x8*>(
              kp + (size_t)(kv0 + 64 + row) * HD + ch * 8);
        }
      }

      // 3) S^T = K Q^T (SWAPPED): sacc[f][r] = S[kv0+f*16+lg*4+r][qbase+lr]
      f32x4 sacc[4] = {};
#pragma unroll
      for (int dk = 0; dk < 4; ++dk) {
        bf16x8 kf[4];
#pragma unroll
        for (int f = 0; f < 4; ++f) {
          const int ch = (dk * 4 + lg) ^ (lr & 7);
          kf[f] = *reinterpret_cast<const bf16x8*>(&lk[cur][f * 16 + lr][ch * 8]);
        }
        __builtin_amdgcn_s_setprio(1);
#pragma unroll
        for (int f = 0; f < 4; ++f)
          sacc[f] = __builtin_amdgcn_mfma_f32_16x16x32_bf16(kf[f], qf[dk], sacc[f], 0, 0, 0);
        __builtin_amdgcn_s_setprio(0);
      }

      if (kt == qt) {  // diagonal tile: mask kv > q
#pragma unroll
        for (int f = 0; f < 4; ++f)
#pragma unroll
          for (int r = 0; r < 4; ++r)
            if (kv0 + f * 16 + lg * 4 + r > qbase + lr) sacc[f][r] = -1e30f;
      }

      // 4) online softmax (exp2 domain), in-lane 16-value reduce + 2 shfl
      float mloc = sacc[0][0];
#pragma unroll
      for (int f = 0; f < 4; ++f)
#pragma unroll
        for (int r = 0; r < 4; ++r) mloc = fmaxf(mloc, sacc[f][r]);
      mloc = fmaxf(mloc, __shfl_xor(mloc, 16));
      mloc = fmaxf(mloc, __shfl_xor(mloc, 32));

      if (__any(mloc > mrun + 8.f)) {   // defer-max rescale (rare)
        float mnew = fmaxf(mrun, mloc);
        float sf = exp2f(mrun - mnew);
        mrun = mnew;
        lrun *= sf;
        float sfr[4];
#pragma unroll
        for (int r = 0; r < 4; ++r)
          sfr[r] = __shfl(sf, (l & 48) | (lg * 4 + r));  // sf of o's q-row
#pragma unroll
        for (int cc = 0; cc < 8; ++cc)
#pragma unroll
          for (int r = 0; r < 4; ++r) o[cc][r] *= sfr[r];
      }

      float ssum = 0.f;
#pragma unroll
      for (int f = 0; f < 4; ++f)
#pragma unroll
        for (int r = 0; r < 4; ++r) {
          sacc[f][r] = exp2f(sacc[f][r] - mrun);   // bounded by 2^8
          ssum += sacc[f][r];
        }
      ssum += __shfl_xor(ssum, 16);
      ssum += __shfl_xor(ssum, 32);
      lrun += ssum;

      // 5) P -> LDS [q][kv] (packed 4x bf16; wave-private, no barrier)
#pragma unroll
      for (int f = 0; f < 4; ++f) {
        bf16x4 pk;
#pragma unroll
        for (int r = 0; r < 4; ++r) pk[r] = (bf16_t)sacc[f][r];
        *reinterpret_cast<bf16x4*>(&lp[w][lr][f * 16 + lg * 4]) = pk;
      }

      // 6) O += P V (A-operand read identical to v5)
#pragma unroll
      for (int ks = 0; ks < 2; ++ks) {
        bf16x8 pf = *reinterpret_cast<const bf16x8*>(&lp[w][lr][ks * 32 + lg * 8]);
        __builtin_amdgcn_s_setprio(1);
#pragma unroll
        for (int cc = 0; cc < 8; ++cc)
          o[cc] = __builtin_amdgcn_mfma_f32_16x16x32_bf16(pf, vf[cc * 2 + ks], o[cc], 0, 0, 0);
        __builtin_amdgcn_s_setprio(0);
      }

      // 7) write prefetched K into the other buffer; single barrier/iter
      if (kt < qt) {
#pragma unroll
        for (int c = 0; c < 4; ++c) {
          int p = tid + c * 256, row = p >> 4, ch = (p & 15) ^ (row & 7);
          *reinterpret_cast<bf16x8*>(&lk[cur ^ 1][row][ch * 8]) = kreg[c];
        }
      }
      __syncthreads();
    }

    // normalize + write y as [b][t][h*128+d] (GEMM2 A layout)
    float linv = 1.0f / lrun;
    float linvr[4];
#pragma unroll
    for (int r = 0; r < 4; ++r)
      linvr[r] = __shfl(linv, (l & 48) | (lg * 4 + r));
#pragma unroll
    for (int cc = 0; cc < 8; ++cc)
#pragma unroll
      for (int r = 0; r < 4; ++r) {
        int t = qbase + lg * 4 + r;
        float val = o[cc][r] * linvr[r];
        yg[((size_t)(b * T_SEQ + t)) * C_DIM + h * HD + cc * 16 + lr] = (bf16_t)val;
      }
  }
}

// ---------------- launch ----------------
extern "C" void kernel_launch(void* const* d_in, const int* in_sizes, int n_in,
                              void* d_out, int out_size, void* d_ws, size_t ws_size,
                              hipStream_t stream) {
  (void)in_sizes; (void)n_in; (void)out_size; (void)ws_size;
  const float* x     = (const float*)d_in[0];
  const float* Wqkv  = (const float*)d_in[1];
  const float* Wproj = (const float*)d_in[2];
  float* out = (float*)d_out;

  char* ws = (char*)d_ws;
  float*  ctab   = (float*)(ws + 0);          // 512 KB
  float*  stab   = (float*)(ws + 524288);     // 512 KB
  bf16_t* xb     = (bf16_t*)(ws + 1048576);   // 16 MB
  bf16_t* wqkvT  = (bf16_t*)(ws + 17825792);  // 24 MB  [6144][2048]
  bf16_t* wprojT = (bf16_t*)(ws + 42991616);  // 8 MB   [2048][2048]
  bf16_t* qws    = (bf16_t*)(ws + 51380224);  // 16 MB  [b][h][t][d]
  bf16_t* kws    = (bf16_t*)(ws + 68157440);  // 16 MB  [b][h][t][d]
  bf16_t* vtws   = (bf16_t*)(ws + 84934656);  // 16 MB  [b][h][d][t]
  bf16_t* yws    = (bf16_t*)(ws + 101711872); // 16 MB  [b*t][h*d]

  rope_table_kernel<<<512, 256, 0, stream>>>(ctab, stab);
  convert_bf16_kernel<<<8192, 256, 0, stream>>>(x, xb, 2097152);
  transpose_convert_kernel<<<dim3(192, 64), dim3(32, 8), 0, stream>>>(Wqkv, wqkvT, 2048, 6144);
  transpose_convert_kernel<<<dim3(64, 64), dim3(32, 8), 0, stream>>>(Wproj, wprojT, 2048, 2048);

  // GEMM1: M=4096 x N=6144 -> 1536 blocks; XCD n-band (6 cols/XCD)
  gemm_bf16_kernel<0><<<1536, 256, 0, stream>>>(
      xb, wqkvT, nullptr, qws, kws, vtws, ctab, stab);

  attention_kernel<<<512, 256, 0, stream>>>(qws, kws, vtws, yws);

  // GEMM2: M=4096 x N=2048 -> 512 blocks; XCD m-band (4 rows/XCD)
  gemm_bf16_kernel<1><<<512, 256, 0, stream>>>(
      yws, wprojT, out, nullptr, nullptr, nullptr, nullptr, nullptr);
}

// Round 19
// 355.372 us; speedup vs baseline: 1.0293x; 1.0293x over previous
//
#include <hip/hip_runtime.h>
#include <cmath>

typedef __bf16 bf16_t;
typedef __bf16 bf16x8 __attribute__((ext_vector_type(8)));
typedef __bf16 bf16x4 __attribute__((ext_vector_type(4)));
typedef float f32x4 __attribute__((ext_vector_type(4)));

#define T_SEQ 2048
#define C_DIM 2048
#define H_NUM 16
#define HD    128
#define KK    2048  // reduction dim for both GEMMs

// ---------------- RoPE cos/sin table: [T][64] ----------------
__global__ void rope_table_kernel(float* __restrict__ ct, float* __restrict__ st) {
  int idx = blockIdx.x * 256 + threadIdx.x;   // T*64 = 131072
  int t = idx >> 6, i = idx & 63;
  double invf = pow(10000.0, -(double)i / 64.0);  // base^(-2i/hd)
  float ang = (float)t * (float)invf;             // fp32 rounding like reference
  ct[idx] = cosf(ang);
  st[idx] = sinf(ang);
}

// ---------------- fp32 -> bf16 elementwise ----------------
__global__ void convert_bf16_kernel(const float* __restrict__ in, bf16_t* __restrict__ out, int n4) {
  int i = blockIdx.x * 256 + threadIdx.x;
  if (i >= n4) return;
  const float4 v = reinterpret_cast<const float4*>(in)[i];
  bf16x4 o;
  o[0] = (bf16_t)v.x; o[1] = (bf16_t)v.y; o[2] = (bf16_t)v.z; o[3] = (bf16_t)v.w;
  reinterpret_cast<bf16x4*>(out)[i] = o;
}

// ---------------- transpose+convert: in[R][Cc] f32 -> out[Cc][R] bf16 ----------------
__global__ void transpose_convert_kernel(const float* __restrict__ in, bf16_t* __restrict__ out,
                                         int R, int Cc) {
  __shared__ __align__(16) bf16_t tile[32][33];
  int c0 = blockIdx.x * 32, r0 = blockIdx.y * 32;
  int tx = threadIdx.x, ty = threadIdx.y;
#pragma unroll
  for (int i = 0; i < 4; ++i)
    tile[ty + 8 * i][tx] = (bf16_t)in[(size_t)(r0 + ty + 8 * i) * Cc + c0 + tx];
  __syncthreads();
#pragma unroll
  for (int i = 0; i < 4; ++i)
    out[(size_t)(c0 + ty + 8 * i) * R + r0 + tx] = tile[tx][ty + 8 * i];
}

// ---------------- GEMM: A[M][K] bf16 @ Bt[N][K] bf16 -> epilogue ----------------
// r13 structure (measured best) with ONE change vs r17: __launch_bounds__(256,3).
// Unconfounded occupancy test: VGPR cap at 3 waves/SIMD ~168 >> 76 (no
// register squeeze -- r18's (256,4) forced 76->64 and regressed), LDS
// 3x32KB=96 <= 160KB -> 3 blocks/CU ceiling (was 2).
template <int MODE>
__global__ __launch_bounds__(256, 3)
void gemm_bf16_kernel(const bf16_t* __restrict__ A, const bf16_t* __restrict__ Bt,
                      float* __restrict__ outF,
                      bf16_t* __restrict__ qws, bf16_t* __restrict__ kws,
                      bf16_t* __restrict__ vtws,
                      const float* __restrict__ ctab, const float* __restrict__ stab) {
  const int tid = threadIdx.x;
  const int l = tid & 63, w = tid >> 6;
  const int wr = w >> 1, wc = w & 1;
  const int lg = l >> 4, lr = l & 15;

  // per-XCD band mapping
  const int g = blockIdx.x & 7;
  const int q = blockIdx.x >> 3;
  int m0, n0;
  if (MODE == 0) {            // n-band: 6 cols per XCD, n-fast
    m0 = (q / 6) * 128;
    n0 = (g * 6 + (q % 6)) * 128;
  } else {                    // m-band: 4 rows per XCD, m-fast
    m0 = (g * 4 + (q & 3)) * 128;
    n0 = (q >> 2) * 128;
  }

  __shared__ __align__(16) bf16_t la[128][64];
  __shared__ __align__(16) bf16_t lb[128][64];

  f32x4 acc[4][4] = {};
  bf16x8 ra[4], rb[4];

  const bf16_t* Ab = A + (size_t)m0 * KK;
  const bf16_t* Bb = Bt + (size_t)n0 * KK;

#pragma unroll
  for (int c = 0; c < 4; ++c) {
    int p = tid + c * 256, row = p >> 3, kc = p & 7;
    ra[c] = *reinterpret_cast<const bf16x8*>(Ab + (size_t)row * KK + kc * 8);
    rb[c] = *reinterpret_cast<const bf16x8*>(Bb + (size_t)row * KK + kc * 8);
  }

  for (int kt = 0; kt < KK / 64; ++kt) {
    __syncthreads();  // previous tile's reads done
#pragma unroll
    for (int c = 0; c < 4; ++c) {
      int p = tid + c * 256, row = p >> 3;
      int kcw = (p & 7) ^ (row & 7);   // XOR layout: phys chunk holds global^row
      *reinterpret_cast<bf16x8*>(&la[row][kcw * 8]) = ra[c];
      *reinterpret_cast<bf16x8*>(&lb[row][kcw * 8]) = rb[c];
    }
    __syncthreads();
    if (kt + 1 < KK / 64) {  // prefetch next tile; latency hides under MFMAs
#pragma unroll
      for (int c = 0; c < 4; ++c) {
        int p = tid + c * 256, row = p >> 3, kc = p & 7;
        ra[c] = *reinterpret_cast<const bf16x8*>(Ab + (size_t)row * KK + (kt + 1) * 64 + kc * 8);
        rb[c] = *reinterpret_cast<const bf16x8*>(Bb + (size_t)row * KK + (kt + 1) * 64 + kc * 8);
      }
    }
#pragma unroll
    for (int ks = 0; ks < 2; ++ks) {
      bf16x8 af[4], bfr[4];
      const int pc = ((ks * 4 + lg) ^ (lr & 7)) * 8;  // matching read XOR
#pragma unroll
      for (int i = 0; i < 4; ++i) {
        af[i]  = *reinterpret_cast<const bf16x8*>(&la[wr * 64 + i * 16 + lr][pc]);
        bfr[i] = *reinterpret_cast<const bf16x8*>(&lb[wc * 64 + i * 16 + lr][pc]);
      }
#pragma unroll
      for (int mi = 0; mi < 4; ++mi)
#pragma unroll
        for (int ni = 0; ni < 4; ++ni)
          acc[mi][ni] = __builtin_amdgcn_mfma_f32_16x16x32_bf16(af[mi], bfr[ni], acc[mi][ni], 0, 0, 0);
    }
  }

  if (MODE == 0) {
    const int sec = n0 >> 11;           // 0=q 1=k 2=v (block never crosses sections)
    const int h = (n0 & 2047) >> 7;     // one head per 128-col block
#pragma unroll
    for (int mi = 0; mi < 4; ++mi) {
#pragma unroll
      for (int ni = 0; ni < 4; ++ni) {
        const int d = wc * 64 + ni * 16 + lr;   // 0..127
#pragma unroll
        for (int r = 0; r < 4; ++r) {
          const int m = m0 + wr * 64 + mi * 16 + lg * 4 + r;
          const int b = m >> 11, t = m & 2047;
          float val = acc[mi][ni][r];
          if (sec < 2) {
            // RoPE pair (d, d^1) sits in lane l^1 (D-frag col = lane&15)
            float partner = __shfl_xor(val, 1);
            const int fi = d >> 1;
            float cth = ctab[t * 64 + fi], sth = stab[t * 64 + fi];
            float ov = (d & 1) ? (val * cth + partner * sth)
                               : (val * cth - partner * sth);
            // q scale = (1/sqrt(128)) * log2(e): softmax runs in exp2 domain
            if (sec == 0) ov *= 0.127517445f;
            bf16_t* dst = (sec == 0) ? qws : kws;
            dst[((size_t)(b * H_NUM + h) * T_SEQ + t) * HD + d] = (bf16_t)ov;
          } else {
            // v stored transposed [b][h][d][t] so PV B-operand is kv-contiguous
            vtws[((size_t)(b * H_NUM + h) * HD + d) * T_SEQ + t] = (bf16_t)val;
          }
        }
      }
    }
  } else {
#pragma unroll
    for (int mi = 0; mi < 4; ++mi)
#pragma unroll
      for (int ni = 0; ni < 4; ++ni) {
        const int n = n0 + wc * 64 + ni * 16 + lr;
#pragma unroll
        for (int r = 0; r < 4; ++r) {
          const int m = m0 + wr * 64 + mi * 16 + lg * 4 + r;
          outF[(size_t)m * C_DIM + n] = acc[mi][ni][r];
        }
      }
  }
}

// ---------------- causal flash attention (v7: swapped-QK^T softmax) ----------------
// r13-measured best: 512 paired blocks {31-p, p}, XCD-pinned (4 bh x 1MB K/V
// per XCD ~= L2; FETCH ~25MB), K dbuf + XOR swizzle, V-in-regs issued early,
// swapped QK^T (lane owns q-row), exp2 domain, defer-max, launch_bounds(256,2),
// VGPR 120, no spills. FROZEN.
__global__ __launch_bounds__(256, 2)
void attention_kernel(const bf16_t* __restrict__ qg, const bf16_t* __restrict__ kg,
                      const bf16_t* __restrict__ vtg, bf16_t* __restrict__ yg) {
  const int tid = threadIdx.x;
  const int l = tid & 63, w = tid >> 6;
  const int lg = l >> 4, lr = l & 15;

  const int g = blockIdx.x & 7;
  const int j = blockIdx.x >> 3;
  const int bh = 4 * g + (j >> 4);
  const int pair = j & 15;
  const int b = bh >> 4, h = bh & 15;

  __shared__ __align__(16) bf16_t lk[2][64][128];
  __shared__ __align__(16) bf16_t lp[4][16][72];   // per-wave P [q][kv], +8 pad

  const bf16_t* qp = qg + (size_t)bh * T_SEQ * HD;
  const bf16_t* kp = kg + (size_t)bh * T_SEQ * HD;
  const bf16_t* vp = vtg + (size_t)bh * HD * T_SEQ;

#pragma unroll 1
  for (int half = 0; half < 2; ++half) {
    const int qt = (half == 0) ? (31 - pair) : pair;
    const int qbase = qt * 64 + w * 16;

    bf16x8 qf[4];
#pragma unroll
    for (int dk = 0; dk < 4; ++dk)
      qf[dk] = *reinterpret_cast<const bf16x8*>(qp + (size_t)(qbase + lr) * HD + dk * 32 + lg * 8);

    f32x4 o[8] = {};
    float mrun = -1e30f, lrun = 0.f;   // scalar: this lane's q-row = qbase+lr

    // prologue: stage K tile 0 into lk[0]
    bf16x8 kreg[4];
#pragma unroll
    for (int c = 0; c < 4; ++c) {
      int p = tid + c * 256, row = p >> 4, ch = p & 15;
      kreg[c] = *reinterpret_cast<const bf16x8*>(kp + (size_t)row * HD + ch * 8);
    }
    __syncthreads();  // prior half's lk reads complete before overwrite
#pragma unroll
    for (int c = 0; c < 4; ++c) {
      int p = tid + c * 256, row = p >> 4, ch = (p & 15) ^ (row & 7);
      *reinterpret_cast<bf16x8*>(&lk[0][row][ch * 8]) = kreg[c];
    }
    __syncthreads();

#pragma unroll 1
    for (int kt = 0; kt <= qt; ++kt) {
      const int cur = kt & 1;
      const int kv0 = kt * 64;

      // 1) V fragments for THIS tile: issue first (needed mid-iteration)
      bf16x8 vf[16];
#pragma unroll
      for (int cc = 0; cc < 8; ++cc)
#pragma unroll
        for (int ks = 0; ks < 2; ++ks)
          vf[cc * 2 + ks] = *reinterpret_cast<const bf16x8*>(
              vp + (size_t)(cc * 16 + lr) * T_SEQ + kv0 + ks * 32 + lg * 8);

      // 2) K prefetch for NEXT tile (stays in flight past the V wait)
      if (kt < qt) {
#pragma unroll
        for (int c = 0; c < 4; ++c) {
          int p = tid + c * 256, row = p >> 4, ch = p & 15;
          kreg[c] = *reinterpret_cast<const bf16x8*>(
              kp + (size_t)(kv0 + 64 + row) * HD + ch * 8);
        }
      }

      // 3) S^T = K Q^T (SWAPPED): sacc[f][r] = S[kv0+f*16+lg*4+r][qbase+lr]
      f32x4 sacc[4] = {};
#pragma unroll
      for (int dk = 0; dk < 4; ++dk) {
        bf16x8 kf[4];
#pragma unroll
        for (int f = 0; f < 4; ++f) {
          const int ch = (dk * 4 + lg) ^ (lr & 7);
          kf[f] = *reinterpret_cast<const bf16x8*>(&lk[cur][f * 16 + lr][ch * 8]);
        }
        __builtin_amdgcn_s_setprio(1);
#pragma unroll
        for (int f = 0; f < 4; ++f)
          sacc[f] = __builtin_amdgcn_mfma_f32_16x16x32_bf16(kf[f], qf[dk], sacc[f], 0, 0, 0);
        __builtin_amdgcn_s_setprio(0);
      }

      if (kt == qt) {  // diagonal tile: mask kv > q
#pragma unroll
        for (int f = 0; f < 4; ++f)
#pragma unroll
          for (int r = 0; r < 4; ++r)
            if (kv0 + f * 16 + lg * 4 + r > qbase + lr) sacc[f][r] = -1e30f;
      }

      // 4) online softmax (exp2 domain), in-lane 16-value reduce + 2 shfl
      float mloc = sacc[0][0];
#pragma unroll
      for (int f = 0; f < 4; ++f)
#pragma unroll
        for (int r = 0; r < 4; ++r) mloc = fmaxf(mloc, sacc[f][r]);
      mloc = fmaxf(mloc, __shfl_xor(mloc, 16));
      mloc = fmaxf(mloc, __shfl_xor(mloc, 32));

      if (__any(mloc > mrun + 8.f)) {   // defer-max rescale (rare)
        float mnew = fmaxf(mrun, mloc);
        float sf = exp2f(mrun - mnew);
        mrun = mnew;
        lrun *= sf;
        float sfr[4];
#pragma unroll
        for (int r = 0; r < 4; ++r)
          sfr[r] = __shfl(sf, (l & 48) | (lg * 4 + r));  // sf of o's q-row
#pragma unroll
        for (int cc = 0; cc < 8; ++cc)
#pragma unroll
          for (int r = 0; r < 4; ++r) o[cc][r] *= sfr[r];
      }

      float ssum = 0.f;
#pragma unroll
      for (int f = 0; f < 4; ++f)
#pragma unroll
        for (int r = 0; r < 4; ++r) {
          sacc[f][r] = exp2f(sacc[f][r] - mrun);   // bounded by 2^8
          ssum += sacc[f][r];
        }
      ssum += __shfl_xor(ssum, 16);
      ssum += __shfl_xor(ssum, 32);
      lrun += ssum;

      // 5) P -> LDS [q][kv] (packed 4x bf16; wave-private, no barrier)
#pragma unroll
      for (int f = 0; f < 4; ++f) {
        bf16x4 pk;
#pragma unroll
        for (int r = 0; r < 4; ++r) pk[r] = (bf16_t)sacc[f][r];
        *reinterpret_cast<bf16x4*>(&lp[w][lr][f * 16 + lg * 4]) = pk;
      }

      // 6) O += P V (A-operand read identical to v5)
#pragma unroll
      for (int ks = 0; ks < 2; ++ks) {
        bf16x8 pf = *reinterpret_cast<const bf16x8*>(&lp[w][lr][ks * 32 + lg * 8]);
        __builtin_amdgcn_s_setprio(1);
#pragma unroll
        for (int cc = 0; cc < 8; ++cc)
          o[cc] = __builtin_amdgcn_mfma_f32_16x16x32_bf16(pf, vf[cc * 2 + ks], o[cc], 0, 0, 0);
        __builtin_amdgcn_s_setprio(0);
      }

      // 7) write prefetched K into the other buffer; single barrier/iter
      if (kt < qt) {
#pragma unroll
        for (int c = 0; c < 4; ++c) {
          int p = tid + c * 256, row = p >> 4, ch = (p & 15) ^ (row & 7);
          *reinterpret_cast<bf16x8*>(&lk[cur ^ 1][row][ch * 8]) = kreg[c];
        }
      }
      __syncthreads();
    }

    // normalize + write y as [b][t][h*128+d] (GEMM2 A layout)
    float linv = 1.0f / lrun;
    float linvr[4];
#pragma unroll
    for (int r = 0; r < 4; ++r)
      linvr[r] = __shfl(linv, (l & 48) | (lg * 4 + r));
#pragma unroll
    for (int cc = 0; cc < 8; ++cc)
#pragma unroll
      for (int r = 0; r < 4; ++r) {
        int t = qbase + lg * 4 + r;
        float val = o[cc][r] * linvr[r];
        yg[((size_t)(b * T_SEQ + t)) * C_DIM + h * HD + cc * 16 + lr] = (bf16_t)val;
      }
  }
}

// ---------------- launch ----------------
extern "C" void kernel_launch(void* const* d_in, const int* in_sizes, int n_in,
                              void* d_out, int out_size, void* d_ws, size_t ws_size,
                              hipStream_t stream) {
  (void)in_sizes; (void)n_in; (void)out_size; (void)ws_size;
  const float* x     = (const float*)d_in[0];
  const float* Wqkv  = (const float*)d_in[1];
  const float* Wproj = (const float*)d_in[2];
  float* out = (float*)d_out;

  char* ws = (char*)d_ws;
  float*  ctab   = (float*)(ws + 0);          // 512 KB
  float*  stab   = (float*)(ws + 524288);     // 512 KB
  bf16_t* xb     = (bf16_t*)(ws + 1048576);   // 16 MB
  bf16_t* wqkvT  = (bf16_t*)(ws + 17825792);  // 24 MB  [6144][2048]
  bf16_t* wprojT = (bf16_t*)(ws + 42991616);  // 8 MB   [2048][2048]
  bf16_t* qws    = (bf16_t*)(ws + 51380224);  // 16 MB  [b][h][t][d]
  bf16_t* kws    = (bf16_t*)(ws + 68157440);  // 16 MB  [b][h][t][d]
  bf16_t* vtws   = (bf16_t*)(ws + 84934656);  // 16 MB  [b][h][d][t]
  bf16_t* yws    = (bf16_t*)(ws + 101711872); // 16 MB  [b*t][h*d]

  rope_table_kernel<<<512, 256, 0, stream>>>(ctab, stab);
  convert_bf16_kernel<<<8192, 256, 0, stream>>>(x, xb, 2097152);
  transpose_convert_kernel<<<dim3(192, 64), dim3(32, 8), 0, stream>>>(Wqkv, wqkvT, 2048, 6144);
  transpose_convert_kernel<<<dim3(64, 64), dim3(32, 8), 0, stream>>>(Wproj, wprojT, 2048, 2048);

  // GEMM1: M=4096 x N=6144 -> 1536 blocks; XCD n-band (6 cols/XCD)
  gemm_bf16_kernel<0><<<1536, 256, 0, stream>>>(
      xb, wqkvT, nullptr, qws, kws, vtws, ctab, stab);

  attention_kernel<<<512, 256, 0, stream>>>(qws, kws, vtws, yws);

  // GEMM2: M=4096 x N=2048 -> 512 blocks; XCD m-band (4 rows/XCD)
  gemm_bf16_kernel<1><<<512, 256, 0, stream>>>(
      yws, wprojT, out, nullptr, nullptr, nullptr, nullptr, nullptr);
}